// Round 5
// baseline (245.601 us; speedup 1.0000x reference)
//
#include <hip/hip_runtime.h>
#include <math.h>

#define IN_CH 256
#define OUT_CH 64
#define KCH 64
#define XSTR 68     // x-tile LDS row stride (floats): 68%32=4 -> 2-way max (free)
#define SCHUNK 512  // scan elements per block (needs n <= 256*SCHUNK = 131072)

// ---------- monotonic float<->uint mapping for atomic max ----------
__device__ __forceinline__ unsigned fmap(float f) {
  unsigned u = __float_as_uint(f);
  return (u & 0x80000000u) ? ~u : (u | 0x80000000u);
}
__device__ __forceinline__ float funmap(unsigned u) {
  return (u & 0x80000000u) ? __uint_as_float(u & 0x7fffffffu) : __uint_as_float(~u);
}

// ---------- K1: Wh = x @ W ; e = Wh . (a_src + a_dst) ; gmax = max(e) ----------
// 512 threads (8 waves), 64 rows/block, thread = 2 rows x 4 cols.
__global__ __launch_bounds__(512) void gat_gemm_e(
    const float* __restrict__ x, const float* __restrict__ W,
    const float* __restrict__ a_src, const float* __restrict__ a_dst,
    float* __restrict__ Wh, float* __restrict__ e, unsigned* __restrict__ gmax, int n)
{
  __shared__ float Wl[KCH * OUT_CH];   // 16 KB  [kk][o]
  __shared__ float xl[64 * XSTR];      // 17.4 KB [row][kk]
  const int tid = threadIdx.x;
  const int row0 = blockIdx.x * 64;
  int nrows = n - row0; if (nrows > 64) nrows = 64;

  const int wave = tid >> 6, lane = tid & 63;
  const int rs = lane >> 4, cg = lane & 15;
  const int rbase = wave * 8 + rs * 2;   // first of my 2 rows (tile-local)
  const int oc = cg * 4;                 // first of my 4 channels

  float acc[2][4];
#pragma unroll
  for (int r = 0; r < 2; ++r)
#pragma unroll
    for (int c = 0; c < 4; ++c) acc[r][c] = 0.f;

  for (int k0 = 0; k0 < IN_CH; k0 += KCH) {
    // stage W chunk: 1024 float4 / 512 threads
    {
      const float4* src = (const float4*)(W + (size_t)k0 * OUT_CH);
      float4* dst = (float4*)Wl;
      dst[tid] = src[tid];
      dst[tid + 512] = src[tid + 512];
    }
    // stage x chunk (nrows * 16 float4)
    for (int i = tid; i < nrows * 16; i += 512) {
      int r = i >> 4, kc = (i & 15) << 2;
      float4 v = *(const float4*)(x + (size_t)(row0 + r) * IN_CH + k0 + kc);
      *(float4*)(xl + r * XSTR + kc) = v;
    }
    __syncthreads();
#pragma unroll 4
    for (int k = 0; k < KCH; k += 4) {
      float wv[4][4], xv[2][4];
#pragma unroll
      for (int i = 0; i < 4; ++i)
        *(float4*)&wv[i][0] = *(const float4*)(Wl + (k + i) * OUT_CH + oc);
#pragma unroll
      for (int r = 0; r < 2; ++r)
        *(float4*)&xv[r][0] = *(const float4*)(xl + (rbase + r) * XSTR + k);
#pragma unroll
      for (int r = 0; r < 2; ++r)
#pragma unroll
        for (int i = 0; i < 4; ++i)
#pragma unroll
          for (int c = 0; c < 4; ++c)
            acc[r][c] = fmaf(xv[r][i], wv[i][c], acc[r][c]);
    }
    __syncthreads();
  }

  float4 as4 = *(const float4*)(a_src + oc);
  float4 ad4 = *(const float4*)(a_dst + oc);
  float asd[4] = {as4.x + ad4.x, as4.y + ad4.y, as4.z + ad4.z, as4.w + ad4.w};

  float vmax = -INFINITY;
#pragma unroll
  for (int r = 0; r < 2; ++r) {
    int rt = rbase + r;
    int row = row0 + rt;
    bool ok = rt < nrows;
    if (ok) {
      float4 o4;
      o4.x = acc[r][0]; o4.y = acc[r][1]; o4.z = acc[r][2]; o4.w = acc[r][3];
      *(float4*)(Wh + (size_t)row * OUT_CH + oc) = o4;
    }
    float v = acc[r][0]*asd[0] + acc[r][1]*asd[1] + acc[r][2]*asd[2] + acc[r][3]*asd[3];
    v += __shfl_xor(v, 1); v += __shfl_xor(v, 2); v += __shfl_xor(v, 4); v += __shfl_xor(v, 8);
    if (ok) {
      if (cg == 0) e[row] = v;
      vmax = fmaxf(vmax, v);
    }
  }
  vmax = fmaxf(vmax, __shfl_xor(vmax, 16));
  vmax = fmaxf(vmax, __shfl_xor(vmax, 32));
  if (lane == 0) atomicMax(gmax, fmap(vmax));
}

// ---------- K2: detect int64 vs int32 edge_index ----------
__global__ void gat_detect64(const unsigned* __restrict__ eidx, unsigned* __restrict__ flag, int npairs)
{
  unsigned v = 0;
  for (int i = threadIdx.x; i < npairs; i += blockDim.x) v |= eidx[2 * i + 1];
#pragma unroll
  for (int m = 32; m >= 1; m >>= 1) v |= __shfl_xor(v, m);
  if ((threadIdx.x & 63) == 0) atomicOr(flag, v);
}

// ---------- K3: count degrees (reads only the col half of eidx) ----------
__global__ void gat_pass1(
    const void* __restrict__ eidx, const unsigned* __restrict__ flag,
    int* __restrict__ cnt, int E)
{
  int j = blockIdx.x * blockDim.x + threadIdx.x;
  if (j >= E) return;
  int c;
  if (*flag == 0) {  // int64: low word of element E+j
    const unsigned* p = (const unsigned*)eidx;
    c = (int)p[2 * ((size_t)E + j)];
  } else {
    const int* p = (const int*)eidx;
    c = p[(size_t)E + j];
  }
  atomicAdd(cnt + c, 1);
}

// ---------- K4a/b/c: hierarchical exclusive scan of cnt -> segp, cursor ----------
__global__ __launch_bounds__(256) void scan_partial(
    const int* __restrict__ cnt, int* __restrict__ bsum, int n)
{
  int base = blockIdx.x * SCHUNK;
  int tid = threadIdx.x;
  int s = 0;
  int i0 = base + tid, i1 = base + tid + 256;
  if (i0 < n) s += cnt[i0];
  if (i1 < n) s += cnt[i1];
#pragma unroll
  for (int m = 1; m < 64; m <<= 1) s += __shfl_xor(s, m);
  __shared__ int ws[4];
  if ((tid & 63) == 0) ws[tid >> 6] = s;
  __syncthreads();
  if (tid == 0) bsum[blockIdx.x] = ws[0] + ws[1] + ws[2] + ws[3];
}

__global__ __launch_bounds__(256) void scan_bsum(
    int* __restrict__ bsum, int* __restrict__ segp, int nb, int n, int E)
{
  __shared__ int sh[256];
  int tid = threadIdx.x;
  int v = (tid < nb) ? bsum[tid] : 0;
  sh[tid] = v;
  __syncthreads();
  for (int off = 1; off < 256; off <<= 1) {
    int add = (tid >= off) ? sh[tid - off] : 0;
    __syncthreads();
    sh[tid] += add;
    __syncthreads();
  }
  if (tid < nb) bsum[tid] = sh[tid] - v;   // exclusive block offsets
  if (tid == 0) segp[n] = E;
}

__global__ __launch_bounds__(256) void scan_final(
    const int* __restrict__ cnt, const int* __restrict__ bsum,
    int* __restrict__ segp, int* __restrict__ cursor, int n)
{
  int base = blockIdx.x * SCHUNK;
  int tid = threadIdx.x;
  int i0 = base + 2 * tid, i1 = i0 + 1;
  int c0 = (i0 < n) ? cnt[i0] : 0;
  int c1 = (i1 < n) ? cnt[i1] : 0;
  int ps = c0 + c1;
  __shared__ int sh[256];
  sh[tid] = ps;
  __syncthreads();
  for (int off = 1; off < 256; off <<= 1) {
    int add = (tid >= off) ? sh[tid - off] : 0;
    __syncthreads();
    sh[tid] += add;
    __syncthreads();
  }
  int excl = sh[tid] - ps + bsum[blockIdx.x];
  if (i0 < n) { segp[i0] = excl;      cursor[i0] = excl; }
  if (i1 < n) { segp[i1] = excl + c0; cursor[i1] = excl + c0; }
}

// ---------- K5: pure CSR scatter — IDX bytes per edge (row id only) ----------
template <typename IDX>
__global__ void gat_scatter(
    const void* __restrict__ eidx, const unsigned* __restrict__ flag,
    int* __restrict__ cursor, IDX* __restrict__ perm, int E)
{
  int j = blockIdx.x * blockDim.x + threadIdx.x;
  if (j >= E) return;
  int r, c;
  if (*flag == 0) {
    const long long* p = (const long long*)eidx;
    r = (int)p[j]; c = (int)p[(size_t)E + j];
  } else {
    const int* p = (const int*)eidx;
    r = p[j]; c = p[(size_t)E + j];
  }
  int pos = atomicAdd(cursor + c, 1);
  perm[pos] = (IDX)r;
}

// ---------- K6: aggregate + ELU; recompute ev in-loop (1 wave/node, lane=channel) ----------
template <typename IDX>
__global__ __launch_bounds__(256) void gat_aggregate(
    const float* __restrict__ Wh, const float* __restrict__ e,
    const unsigned* __restrict__ gmax, const IDX* __restrict__ perm,
    const int* __restrict__ segp, float* __restrict__ out, int n)
{
  int wave = threadIdx.x >> 6, lane = threadIdx.x & 63;
  int c = blockIdx.x * 4 + wave;
  if (c >= n) return;
  int p0 = segp[c], p1 = segp[c + 1];
  float s = 2.0f * funmap(*gmax);
  float ec = e[c] - s;

  float a0 = 0.f, a1 = 0.f, a2 = 0.f, a3 = 0.f;
  float s0 = 0.f, s1 = 0.f, s2 = 0.f, s3 = 0.f;
  int p = p0;
  for (; p + 4 <= p1; p += 4) {
    unsigned r0 = (unsigned)perm[p],     r1 = (unsigned)perm[p + 1];
    unsigned r2 = (unsigned)perm[p + 2], r3 = (unsigned)perm[p + 3];
    float e0 = e[r0], e1 = e[r1], e2 = e[r2], e3 = e[r3];
    float w0 = Wh[(size_t)r0 * OUT_CH + lane];
    float w1 = Wh[(size_t)r1 * OUT_CH + lane];
    float w2 = Wh[(size_t)r2 * OUT_CH + lane];
    float w3 = Wh[(size_t)r3 * OUT_CH + lane];
    float v0 = __expf(e0 + ec), v1 = __expf(e1 + ec);
    float v2 = __expf(e2 + ec), v3 = __expf(e3 + ec);
    a0 = fmaf(v0, w0, a0); s0 += v0;
    a1 = fmaf(v1, w1, a1); s1 += v1;
    a2 = fmaf(v2, w2, a2); s2 += v2;
    a3 = fmaf(v3, w3, a3); s3 += v3;
  }
  for (; p < p1; ++p) {
    unsigned r = (unsigned)perm[p];
    float v = __expf(e[r] + ec);
    a0 = fmaf(v, Wh[(size_t)r * OUT_CH + lane], a0); s0 += v;
  }
  float acc = (a0 + a1) + (a2 + a3);
  float ssum = (s0 + s1) + (s2 + s3);
  float rden = (p1 > p0) ? 1.0f / ssum : 0.0f;  // empty segment -> elu(0)=0
  acc *= rden;
  out[(size_t)c * OUT_CH + lane] = acc > 0.f ? acc : expm1f(acc);
}

extern "C" void kernel_launch(void* const* d_in, const int* in_sizes, int n_in,
                              void* d_out, int out_size, void* d_ws, size_t ws_size,
                              hipStream_t stream)
{
  const float* x     = (const float*)d_in[0];
  const void*  eidx  = d_in[1];
  const float* W     = (const float*)d_in[2];
  const float* a_src = (const float*)d_in[3];
  const float* a_dst = (const float*)d_in[4];
  float* out = (float*)d_out;

  const int n = in_sizes[0] / IN_CH;   // 50000
  const int E = in_sizes[1] / 2;       // 800000
  const int nb = (n + SCHUNK - 1) / SCHUNK;

  char* ws = (char*)d_ws;
  size_t off = 0;
  auto alloc = [&](size_t bytes) -> void* {
    void* p = ws + off;
    off = (off + bytes + 255) & ~(size_t)255;
    return p;
  };
  float*    Wh     = (float*)alloc((size_t)n * OUT_CH * 4);
  float*    e      = (float*)alloc((size_t)n * 4);
  void*     perm   = alloc((size_t)E * 4);   // ushort or uint, by n
  int*      cnt    = (int*)alloc((size_t)n * 4);
  int*      segp   = (int*)alloc((size_t)(n + 1) * 4);
  int*      cursor = (int*)alloc((size_t)n * 4);
  int*      bsum   = (int*)alloc((size_t)nb * 4);
  unsigned* gmax   = (unsigned*)alloc(4);
  unsigned* flag   = (unsigned*)alloc(4);

  hipMemsetAsync(cnt,  0, (size_t)n * 4, stream);
  hipMemsetAsync(gmax, 0, 4, stream);
  hipMemsetAsync(flag, 0, 4, stream);

  gat_gemm_e<<<(n + 63) / 64, 512, 0, stream>>>(x, W, a_src, a_dst, Wh, e, gmax, n);
  gat_detect64<<<1, 256, 0, stream>>>((const unsigned*)eidx, flag, 8192);
  gat_pass1<<<(E + 255) / 256, 256, 0, stream>>>(eidx, flag, cnt, E);
  scan_partial<<<nb, 256, 0, stream>>>(cnt, bsum, n);
  scan_bsum<<<1, 256, 0, stream>>>(bsum, segp, nb, n, E);
  scan_final<<<nb, 256, 0, stream>>>(cnt, bsum, segp, cursor, n);
  if (n <= 65536) {
    gat_scatter<unsigned short><<<(E + 255) / 256, 256, 0, stream>>>(
        eidx, flag, cursor, (unsigned short*)perm, E);
    gat_aggregate<unsigned short><<<(n + 3) / 4, 256, 0, stream>>>(
        Wh, e, gmax, (const unsigned short*)perm, segp, out, n);
  } else {
    gat_scatter<unsigned><<<(E + 255) / 256, 256, 0, stream>>>(
        eidx, flag, cursor, (unsigned*)perm, E);
    gat_aggregate<unsigned><<<(n + 3) / 4, 256, 0, stream>>>(
        Wh, e, gmax, (const unsigned*)perm, segp, out, n);
  }
}

// Round 6
// 216.423 us; speedup vs baseline: 1.1348x; 1.1348x over previous
//
#include <hip/hip_runtime.h>
#include <math.h>

#define IN_CH 256
#define OUT_CH 64
#define KCH 64
#define XSTR 68     // x-tile LDS row stride (floats): 68%32=4 -> 2-way max (free)
#define SCHUNK 512  // scan elements per block (needs n <= 256*SCHUNK = 131072)

// ---------- monotonic float<->uint mapping for atomic max ----------
__device__ __forceinline__ unsigned fmap(float f) {
  unsigned u = __float_as_uint(f);
  return (u & 0x80000000u) ? ~u : (u | 0x80000000u);
}
__device__ __forceinline__ float funmap(unsigned u) {
  return (u & 0x80000000u) ? __uint_as_float(u & 0x7fffffffu) : __uint_as_float(~u);
}

// ---------- K1: Wh = x @ W ; e = Wh . (a_src + a_dst) ; gmax = max(e) ----------
// 128 threads (2 waves), 32 rows/block, thread = 4 rows x 4 cols (R4 tile, more blocks).
// LDS 24.7 KB -> 6 blocks/CU; grid 1563 -> ~6 blocks/CU -> ~12 waves/CU.
__global__ __launch_bounds__(128) void gat_gemm_e(
    const float* __restrict__ x, const float* __restrict__ W,
    const float* __restrict__ a_src, const float* __restrict__ a_dst,
    float* __restrict__ Wh, float* __restrict__ e, unsigned* __restrict__ gmax, int n)
{
  __shared__ float Wl[KCH * OUT_CH];   // 16 KB  [kk][o]
  __shared__ float xl[32 * XSTR];      // 8.7 KB [row][kk]
  const int tid = threadIdx.x;
  const int row0 = blockIdx.x * 32;
  int nrows = n - row0; if (nrows > 32) nrows = 32;

  const int wave = tid >> 6, lane = tid & 63;
  const int rs = lane >> 4, cg = lane & 15;
  const int wr = wave * 16 + rs * 4;   // first of my 4 rows (tile-local, 0..31)
  const int oc = cg * 4;               // first of my 4 channels

  float acc[4][4];
#pragma unroll
  for (int r = 0; r < 4; ++r)
#pragma unroll
    for (int c = 0; c < 4; ++c) acc[r][c] = 0.f;

  for (int k0 = 0; k0 < IN_CH; k0 += KCH) {
    // stage W chunk: 1024 float4 / 128 threads
    {
      const float4* src = (const float4*)(W + (size_t)k0 * OUT_CH);
      float4* dst = (float4*)Wl;
#pragma unroll
      for (int i = 0; i < 8; ++i) dst[tid + i * 128] = src[tid + i * 128];
    }
    // stage x chunk (nrows * 16 float4)
    for (int i = tid; i < nrows * 16; i += 128) {
      int r = i >> 4, kc = (i & 15) << 2;
      float4 v = *(const float4*)(x + (size_t)(row0 + r) * IN_CH + k0 + kc);
      *(float4*)(xl + r * XSTR + kc) = v;
    }
    __syncthreads();
#pragma unroll 4
    for (int k = 0; k < KCH; k += 4) {
      float wv[4][4], xv[4][4];
#pragma unroll
      for (int i = 0; i < 4; ++i)
        *(float4*)&wv[i][0] = *(const float4*)(Wl + (k + i) * OUT_CH + oc);
#pragma unroll
      for (int r = 0; r < 4; ++r)
        *(float4*)&xv[r][0] = *(const float4*)(xl + (wr + r) * XSTR + k);
#pragma unroll
      for (int r = 0; r < 4; ++r)
#pragma unroll
        for (int i = 0; i < 4; ++i)
#pragma unroll
          for (int c = 0; c < 4; ++c)
            acc[r][c] = fmaf(xv[r][i], wv[i][c], acc[r][c]);
    }
    __syncthreads();
  }

  float4 as4 = *(const float4*)(a_src + oc);
  float4 ad4 = *(const float4*)(a_dst + oc);
  float asd[4] = {as4.x + ad4.x, as4.y + ad4.y, as4.z + ad4.z, as4.w + ad4.w};

  float vmax = -INFINITY;
#pragma unroll
  for (int r = 0; r < 4; ++r) {
    int rt = wr + r;
    int row = row0 + rt;
    bool ok = rt < nrows;
    if (ok) {
      float4 o4;
      o4.x = acc[r][0]; o4.y = acc[r][1]; o4.z = acc[r][2]; o4.w = acc[r][3];
      *(float4*)(Wh + (size_t)row * OUT_CH + oc) = o4;
    }
    float v = acc[r][0]*asd[0] + acc[r][1]*asd[1] + acc[r][2]*asd[2] + acc[r][3]*asd[3];
    v += __shfl_xor(v, 1); v += __shfl_xor(v, 2); v += __shfl_xor(v, 4); v += __shfl_xor(v, 8);
    if (ok) {
      if (cg == 0) e[row] = v;
      vmax = fmaxf(vmax, v);
    }
  }
  vmax = fmaxf(vmax, __shfl_xor(vmax, 16));
  vmax = fmaxf(vmax, __shfl_xor(vmax, 32));
  if (lane == 0) atomicMax(gmax, fmap(vmax));
}

// ---------- K2: detect int64 vs int32 edge_index ----------
__global__ void gat_detect64(const unsigned* __restrict__ eidx, unsigned* __restrict__ flag, int npairs)
{
  unsigned v = 0;
  for (int i = threadIdx.x; i < npairs; i += blockDim.x) v |= eidx[2 * i + 1];
#pragma unroll
  for (int m = 32; m >= 1; m >>= 1) v |= __shfl_xor(v, m);
  if ((threadIdx.x & 63) == 0) atomicOr(flag, v);
}

// ---------- K3: count degrees (reads only the col half of eidx) ----------
__global__ void gat_pass1(
    const void* __restrict__ eidx, const unsigned* __restrict__ flag,
    int* __restrict__ cnt, int E)
{
  int j = blockIdx.x * blockDim.x + threadIdx.x;
  if (j >= E) return;
  int c;
  if (*flag == 0) {  // int64: low word of element E+j
    const unsigned* p = (const unsigned*)eidx;
    c = (int)p[2 * ((size_t)E + j)];
  } else {
    const int* p = (const int*)eidx;
    c = p[(size_t)E + j];
  }
  atomicAdd(cnt + c, 1);
}

// ---------- K4a/b/c: hierarchical exclusive scan of cnt -> segp, cursor ----------
__global__ __launch_bounds__(256) void scan_partial(
    const int* __restrict__ cnt, int* __restrict__ bsum, int n)
{
  int base = blockIdx.x * SCHUNK;
  int tid = threadIdx.x;
  int s = 0;
  int i0 = base + tid, i1 = base + tid + 256;
  if (i0 < n) s += cnt[i0];
  if (i1 < n) s += cnt[i1];
#pragma unroll
  for (int m = 1; m < 64; m <<= 1) s += __shfl_xor(s, m);
  __shared__ int ws[4];
  if ((tid & 63) == 0) ws[tid >> 6] = s;
  __syncthreads();
  if (tid == 0) bsum[blockIdx.x] = ws[0] + ws[1] + ws[2] + ws[3];
}

__global__ __launch_bounds__(256) void scan_bsum(
    int* __restrict__ bsum, int* __restrict__ segp, int nb, int n, int E)
{
  __shared__ int sh[256];
  int tid = threadIdx.x;
  int v = (tid < nb) ? bsum[tid] : 0;
  sh[tid] = v;
  __syncthreads();
  for (int off = 1; off < 256; off <<= 1) {
    int add = (tid >= off) ? sh[tid - off] : 0;
    __syncthreads();
    sh[tid] += add;
    __syncthreads();
  }
  if (tid < nb) bsum[tid] = sh[tid] - v;   // exclusive block offsets
  if (tid == 0) segp[n] = E;
}

__global__ __launch_bounds__(256) void scan_final(
    const int* __restrict__ cnt, const int* __restrict__ bsum,
    int* __restrict__ segp, int* __restrict__ cursor, int n)
{
  int base = blockIdx.x * SCHUNK;
  int tid = threadIdx.x;
  int i0 = base + 2 * tid, i1 = i0 + 1;
  int c0 = (i0 < n) ? cnt[i0] : 0;
  int c1 = (i1 < n) ? cnt[i1] : 0;
  int ps = c0 + c1;
  __shared__ int sh[256];
  sh[tid] = ps;
  __syncthreads();
  for (int off = 1; off < 256; off <<= 1) {
    int add = (tid >= off) ? sh[tid - off] : 0;
    __syncthreads();
    sh[tid] += add;
    __syncthreads();
  }
  int excl = sh[tid] - ps + bsum[blockIdx.x];
  if (i0 < n) { segp[i0] = excl;      cursor[i0] = excl; }
  if (i1 < n) { segp[i1] = excl + c0; cursor[i1] = excl + c0; }
}

// ---------- K5: pure CSR scatter — IDX bytes per edge (row id only) ----------
template <typename IDX>
__global__ void gat_scatter(
    const void* __restrict__ eidx, const unsigned* __restrict__ flag,
    int* __restrict__ cursor, IDX* __restrict__ perm, int E)
{
  int j = blockIdx.x * blockDim.x + threadIdx.x;
  if (j >= E) return;
  int r, c;
  if (*flag == 0) {
    const long long* p = (const long long*)eidx;
    r = (int)p[j]; c = (int)p[(size_t)E + j];
  } else {
    const int* p = (const int*)eidx;
    r = p[j]; c = p[(size_t)E + j];
  }
  int pos = atomicAdd(cursor + c, 1);
  perm[pos] = (IDX)r;
}

// ---------- K6: aggregate + ELU; recompute ev in-loop (1 wave/node, lane=channel) ----------
template <typename IDX>
__global__ __launch_bounds__(256) void gat_aggregate(
    const float* __restrict__ Wh, const float* __restrict__ e,
    const unsigned* __restrict__ gmax, const IDX* __restrict__ perm,
    const int* __restrict__ segp, float* __restrict__ out, int n)
{
  int wave = threadIdx.x >> 6, lane = threadIdx.x & 63;
  int c = blockIdx.x * 4 + wave;
  if (c >= n) return;
  int p0 = segp[c], p1 = segp[c + 1];
  float s = 2.0f * funmap(*gmax);
  float ec = e[c] - s;

  float a0 = 0.f, a1 = 0.f, a2 = 0.f, a3 = 0.f;
  float s0 = 0.f, s1 = 0.f, s2 = 0.f, s3 = 0.f;
  int p = p0;
  for (; p + 4 <= p1; p += 4) {
    unsigned r0 = (unsigned)perm[p],     r1 = (unsigned)perm[p + 1];
    unsigned r2 = (unsigned)perm[p + 2], r3 = (unsigned)perm[p + 3];
    float e0 = e[r0], e1 = e[r1], e2 = e[r2], e3 = e[r3];
    float w0 = Wh[(size_t)r0 * OUT_CH + lane];
    float w1 = Wh[(size_t)r1 * OUT_CH + lane];
    float w2 = Wh[(size_t)r2 * OUT_CH + lane];
    float w3 = Wh[(size_t)r3 * OUT_CH + lane];
    float v0 = __expf(e0 + ec), v1 = __expf(e1 + ec);
    float v2 = __expf(e2 + ec), v3 = __expf(e3 + ec);
    a0 = fmaf(v0, w0, a0); s0 += v0;
    a1 = fmaf(v1, w1, a1); s1 += v1;
    a2 = fmaf(v2, w2, a2); s2 += v2;
    a3 = fmaf(v3, w3, a3); s3 += v3;
  }
  for (; p < p1; ++p) {
    unsigned r = (unsigned)perm[p];
    float v = __expf(e[r] + ec);
    a0 = fmaf(v, Wh[(size_t)r * OUT_CH + lane], a0); s0 += v;
  }
  float acc = (a0 + a1) + (a2 + a3);
  float ssum = (s0 + s1) + (s2 + s3);
  float rden = (p1 > p0) ? 1.0f / ssum : 0.0f;  // empty segment -> elu(0)=0
  acc *= rden;
  out[(size_t)c * OUT_CH + lane] = acc > 0.f ? acc : expm1f(acc);
}

extern "C" void kernel_launch(void* const* d_in, const int* in_sizes, int n_in,
                              void* d_out, int out_size, void* d_ws, size_t ws_size,
                              hipStream_t stream)
{
  const float* x     = (const float*)d_in[0];
  const void*  eidx  = d_in[1];
  const float* W     = (const float*)d_in[2];
  const float* a_src = (const float*)d_in[3];
  const float* a_dst = (const float*)d_in[4];
  float* out = (float*)d_out;

  const int n = in_sizes[0] / IN_CH;   // 50000
  const int E = in_sizes[1] / 2;       // 800000
  const int nb = (n + SCHUNK - 1) / SCHUNK;

  char* ws = (char*)d_ws;
  size_t off = 0;
  auto alloc = [&](size_t bytes) -> void* {
    void* p = ws + off;
    off = (off + bytes + 255) & ~(size_t)255;
    return p;
  };
  float*    Wh     = (float*)alloc((size_t)n * OUT_CH * 4);
  float*    e      = (float*)alloc((size_t)n * 4);
  void*     perm   = alloc((size_t)E * 4);   // ushort or uint, by n
  int*      cnt    = (int*)alloc((size_t)n * 4);
  int*      segp   = (int*)alloc((size_t)(n + 1) * 4);
  int*      cursor = (int*)alloc((size_t)n * 4);
  int*      bsum   = (int*)alloc((size_t)nb * 4);
  unsigned* gmax   = (unsigned*)alloc(4);
  unsigned* flag   = (unsigned*)alloc(4);

  hipMemsetAsync(cnt,  0, (size_t)n * 4, stream);
  hipMemsetAsync(gmax, 0, 4, stream);
  hipMemsetAsync(flag, 0, 4, stream);

  gat_gemm_e<<<(n + 31) / 32, 128, 0, stream>>>(x, W, a_src, a_dst, Wh, e, gmax, n);
  gat_detect64<<<1, 256, 0, stream>>>((const unsigned*)eidx, flag, 8192);
  gat_pass1<<<(E + 255) / 256, 256, 0, stream>>>(eidx, flag, cnt, E);
  scan_partial<<<nb, 256, 0, stream>>>(cnt, bsum, n);
  scan_bsum<<<1, 256, 0, stream>>>(bsum, segp, nb, n, E);
  scan_final<<<nb, 256, 0, stream>>>(cnt, bsum, segp, cursor, n);
  if (n <= 65536) {
    gat_scatter<unsigned short><<<(E + 255) / 256, 256, 0, stream>>>(
        eidx, flag, cursor, (unsigned short*)perm, E);
    gat_aggregate<unsigned short><<<(n + 3) / 4, 256, 0, stream>>>(
        Wh, e, gmax, (const unsigned short*)perm, segp, out, n);
  } else {
    gat_scatter<unsigned><<<(E + 255) / 256, 256, 0, stream>>>(
        eidx, flag, cursor, (unsigned*)perm, E);
    gat_aggregate<unsigned><<<(n + 3) / 4, 256, 0, stream>>>(
        Wh, e, gmax, (const unsigned*)perm, segp, out, n);
  }
}